// Round 5
// baseline (51.823 us; speedup 1.0000x reference)
//
#include <hip/hip_runtime.h>

// VQ-VAE vector quantizer, MI355X. 3 kernels:
//  K1 vq_prep : z->Abf bf16 [n][d] + znorm (float4 loads, conflict-free LDS transpose);
//               emb->Bbf bf16 + enorm ; emb->emb_t[d][k] f32 ; zero lsum/done
//  K2 vq_argmin : 256x256x256 bf16 MFMA tile, dbuf BK=64 staging; per-wave packed
//               (score,idx) min -> cross-wave LDS min -> planar part[np][row] (no atomics)
//  K3 vq_out : per-thread: min over 4 planes -> idx -> gather emb_t rows (L1) -> out;
//              oct==0 blocks accumulate loss in fixed-point u64, last block finalizes
// z: [16,256,32,32] f32, emb_w: [1024,256] f32
// out: z_q f32 (4194304) ++ loss scalar (1 float)

#define K_CODES 1024
#define D_DIM   256
#define N_VEC   16384
#define ZQ_SIZE 4194304

#define BM 256
#define BN 256

typedef unsigned short ushort_t;
typedef unsigned long long u64;
typedef short bf16x8 __attribute__((ext_vector_type(8)));
typedef float f32x16 __attribute__((ext_vector_type(16)));

__device__ __forceinline__ ushort_t f2bf(float x) {
    unsigned int b = __float_as_uint(x);
    b += 0x7fffu + ((b >> 16) & 1u);   // RNE
    return (ushort_t)(b >> 16);
}

__device__ __forceinline__ void gload_lds16(const void* g, void* l) {
    __builtin_amdgcn_global_load_lds(
        (const __attribute__((address_space(1))) void*)g,
        (__attribute__((address_space(3))) void*)l, 16, 0, 0);
}

// ---------------- K1: prep, blockIdx-branched ----------------
// bid [0,256)   : z -> Abf bf16 [n][256] + znorm[n]  (block = 64 rows, full d)
// bid [256,512) : emb -> Bbf bf16 + enorm ; bid==256 zeroes lsum/done
// bid [512,768) : emb -> emb_t[d][k] f32 transpose
__global__ __launch_bounds__(256) void vq_prep(
        const float* __restrict__ z, const float* __restrict__ emb,
        ushort_t* __restrict__ Abf, float* __restrict__ znorm,
        ushort_t* __restrict__ Bbf, float* __restrict__ enorm,
        float* __restrict__ emb_t, u64* __restrict__ lsum, unsigned* __restrict__ done) {
    __shared__ float lds[256 * 68 + 256];   // 68-float row stride: 16B-aligned, +4-bank/row shift
    const int bid = blockIdx.x;
    const int tid = threadIdx.x;

    if (bid < 256) {
        // 64 rows n0..n0+63 (one (b, hw-quarter)), all 256 d
        const int b = bid >> 4, q = bid & 15;
        const int n0 = b * 1024 + q * 64;
        const float* zb = z + (size_t)b * (256 * 1024) + q * 64;
        float* tile = lds;                  // [256 d][68] f32, cols 0..63 used
        // load: wave covers 4 full 256B rows per instr — fully coalesced
#pragma unroll
        for (int i = 0; i < 16; ++i) {
            const int d = i * 16 + (tid >> 4);
            const int c = (tid & 15) * 4;
            const float4 v = *(const float4*)(zb + (size_t)d * 1024 + c);
            *(float4*)(tile + d * 68 + c) = v;   // bank (4d+4q)%32: uniform, conflict-free
        }
        __syncthreads();
        // transpose-read: lane=hw, 4 consecutive d per iter (banks spread by hw)
        const int hw = tid & 63, ds = tid >> 6;
        float zn = 0.f;
#pragma unroll
        for (int i = 0; i < 16; ++i) {
            const int d0 = ds * 64 + i * 4;
            const float v0 = tile[(d0 + 0) * 68 + hw], v1 = tile[(d0 + 1) * 68 + hw];
            const float v2 = tile[(d0 + 2) * 68 + hw], v3 = tile[(d0 + 3) * 68 + hw];
            zn += v0 * v0 + v1 * v1 + v2 * v2 + v3 * v3;
            ushort4 o;
            o.x = f2bf(v0); o.y = f2bf(v1); o.z = f2bf(v2); o.w = f2bf(v3);
            *(ushort4*)(Abf + (size_t)(n0 + hw) * 256 + d0) = o;
        }
        float* znp = lds + 256 * 68;        // [4][64]
        znp[ds * 64 + hw] = zn;
        __syncthreads();
        if (tid < 64)
            znorm[n0 + tid] = znp[tid] + znp[64 + tid] + znp[128 + tid] + znp[192 + tid];
    } else if (bid < 512) {
        const int w = tid >> 6, l = tid & 63;
        const int k = (bid - 256) * 4 + w;
        const float4 v = *(const float4*)(emb + k * D_DIM + l * 4);
        ushort4 o;
        o.x = f2bf(v.x); o.y = f2bf(v.y); o.z = f2bf(v.z); o.w = f2bf(v.w);
        *(ushort4*)(Bbf + k * D_DIM + l * 4) = o;
        float s = v.x * v.x + v.y * v.y + v.z * v.z + v.w * v.w;
#pragma unroll
        for (int off = 32; off >= 1; off >>= 1) s += __shfl_xor(s, off);
        if (l == 0) enorm[k] = s;
        if (bid == 256 && tid == 0) { *lsum = 0ull; *done = 0u; }
    } else {
        const int t = bid - 512;
        const int kt = t & 31, dt = t >> 5;
        const int c = tid & 31, r4 = tid >> 5;
        const int k0 = kt * 32, d0 = dt * 32;
#pragma unroll
        for (int p = 0; p < 4; ++p) {
            int r = r4 * 4 + p;
            lds[r * 33 + c] = emb[(k0 + r) * D_DIM + d0 + c];
        }
        __syncthreads();
#pragma unroll
        for (int p = 0; p < 4; ++p) {
            int r = r4 * 4 + p;
            emb_t[(d0 + r) * K_CODES + k0 + c] = lds[c * 33 + r];
        }
    }
}

// ---------------- K2: 256x256 MFMA tile -> planar part[np][row] ----------------
__launch_bounds__(512)
__global__ void vq_argmin_mfma(const ushort_t* __restrict__ Abf, const ushort_t* __restrict__ Bbf,
                               const float* __restrict__ enorm, u64* __restrict__ part) {
    __shared__ ushort_t As[2][BM * 64];   // 2 x 32 KB
    __shared__ ushort_t Bs[2][BN * 64];   // 2 x 32 KB
    __shared__ u64 pmin_lds[BM][4];       // 8 KB  (136 KB total, 1 block/CU)

    const int tid = threadIdx.x;          // 512 threads, 8 waves (2m x 4n)
    const int w = tid >> 6, l = tid & 63;
    const int wm = w >> 2, wn = w & 3;
    const int lane31 = l & 31, hi = l >> 5;
    const int mt = blockIdx.x >> 2, np = blockIdx.x & 3;
    const int m0 = mt * BM, n0 = np * BN;

    f32x16 acc[4][2];
#pragma unroll
    for (int mi = 0; mi < 4; ++mi)
#pragma unroll
        for (int ni = 0; ni < 2; ++ni)
#pragma unroll
            for (int r = 0; r < 16; ++r) acc[mi][ni][r] = 0.f;

    // stage chunk t: LDS dest linear; global src pre-permuted so swizzled READ
    // sees logical (r,c) at phys granule c ^ (r&7)  [both-sides-or-neither]
    auto stage = [&](int buf, int t) {
#pragma unroll
        for (int c4 = 0; c4 < 4; ++c4) {
            int g = c4 * 512 + tid;
            int r = g >> 3, cp = g & 7, cg = cp ^ (r & 7);
            gload_lds16(Abf + ((size_t)(m0 + r) * 256 + t * 64 + cg * 8),
                        &As[buf][(size_t)g * 8]);
            gload_lds16(Bbf + ((size_t)(n0 + r) * 256 + t * 64 + cg * 8),
                        &Bs[buf][(size_t)g * 8]);
        }
    };

    auto compute = [&](int buf) {
#pragma unroll
        for (int ks = 0; ks < 4; ++ks) {
            const int cgr = ks * 2 + hi;
            bf16x8 a[4], bb[2];
#pragma unroll
            for (int mi = 0; mi < 4; ++mi) {
                int r = wm * 128 + mi * 32 + lane31;
                int cp = cgr ^ (r & 7);
                a[mi] = *(const bf16x8*)(&As[buf][r * 64 + cp * 8]);
            }
#pragma unroll
            for (int ni = 0; ni < 2; ++ni) {
                int r = wn * 64 + ni * 32 + lane31;
                int cp = cgr ^ (r & 7);
                bb[ni] = *(const bf16x8*)(&Bs[buf][r * 64 + cp * 8]);
            }
#pragma unroll
            for (int mi = 0; mi < 4; ++mi)
#pragma unroll
                for (int ni = 0; ni < 2; ++ni)
                    acc[mi][ni] = __builtin_amdgcn_mfma_f32_32x32x16_bf16(
                        a[mi], bb[ni], acc[mi][ni], 0, 0, 0);
        }
    };

    stage(0, 0);
    __syncthreads();
    for (int t = 0; t < 4; ++t) {
        if (t < 3) stage((t + 1) & 1, t + 1);   // next chunk flies under compute
        compute(t & 1);
        __syncthreads();                         // drains loads + buffer-reuse fence
    }

    // epilogue: score = enorm[k] - 2*dot; pack (score,k); per-wave 32-col min;
    // cross-wave min via LDS; planar coalesced part write (no atomics)
    float en[2]; unsigned int kg[2];
#pragma unroll
    for (int ni = 0; ni < 2; ++ni) {
        int col = n0 + wn * 64 + ni * 32 + lane31;
        en[ni] = enorm[col];
        kg[ni] = (unsigned int)col;
    }
#pragma unroll
    for (int mi = 0; mi < 4; ++mi) {
#pragma unroll
        for (int reg = 0; reg < 16; ++reg) {
            u64 p = ~0ull;
#pragma unroll
            for (int ni = 0; ni < 2; ++ni) {
                float sc = en[ni] - 2.0f * acc[mi][ni][reg];
                unsigned int b = __float_as_uint(sc);
                unsigned int u = b ^ (unsigned int)(((int)b >> 31) | 0x80000000);
                u64 pk = ((u64)u << 32) | kg[ni];
                if (pk < p) p = pk;
            }
#pragma unroll
            for (int off = 16; off >= 1; off >>= 1) {
                u64 q = __shfl_xor(p, off);
                if (q < p) p = q;
            }
            if (lane31 == 0) {
                int rloc = wm * 128 + mi * 32 + (reg & 3) + 8 * (reg >> 2) + 4 * hi;
                pmin_lds[rloc][wn] = p;
            }
        }
    }
    __syncthreads();
    if (tid < 256) {
        u64 a = pmin_lds[tid][0], b = pmin_lds[tid][1];
        u64 c = pmin_lds[tid][2], d = pmin_lds[tid][3];
        u64 m = a < b ? a : b;
        u64 m2 = c < d ? c : d;
        if (m2 < m) m = m2;
        part[(size_t)np * N_VEC + m0 + tid] = m;   // coalesced 2KB store
    }
}

// ---------------- K3: min over planes -> idx -> gather out ; loss ----------------
__global__ __launch_bounds__(256) void vq_out(
        const float* __restrict__ emb_t, const u64* __restrict__ part,
        const float* __restrict__ znorm, float* __restrict__ out,
        float* __restrict__ loss, u64* __restrict__ lsum, unsigned* __restrict__ done) {
    const int bid = blockIdx.x, tid = threadIdx.x;
    const int b = bid >> 5, oct = bid & 31;     // 16 b x 32 d-octets
    const int n = b * 1024 + tid * 4;           // this thread's 4 rows == its 4 hw cols

    u64 m[4];
    {
        ulonglong2 p0 = *(const ulonglong2*)(part + 0 * N_VEC + n);
        ulonglong2 p1 = *(const ulonglong2*)(part + 0 * N_VEC + n + 2);
        m[0] = p0.x; m[1] = p0.y; m[2] = p1.x; m[3] = p1.y;
    }
#pragma unroll
    for (int np = 1; np < 4; ++np) {
        ulonglong2 p0 = *(const ulonglong2*)(part + (size_t)np * N_VEC + n);
        ulonglong2 p1 = *(const ulonglong2*)(part + (size_t)np * N_VEC + n + 2);
        if (p0.x < m[0]) m[0] = p0.x;
        if (p0.y < m[1]) m[1] = p0.y;
        if (p1.x < m[2]) m[2] = p1.x;
        if (p1.y < m[3]) m[3] = p1.y;
    }
    unsigned i0 = (unsigned)(m[0] & 0xffffffffu), i1 = (unsigned)(m[1] & 0xffffffffu);
    unsigned i2 = (unsigned)(m[2] & 0xffffffffu), i3 = (unsigned)(m[3] & 0xffffffffu);

    // gather + write: 8 d rows of emb_t (32 KB, L1-resident per block)
#pragma unroll
    for (int d8 = 0; d8 < 8; ++d8) {
        const int d = oct * 8 + d8;
        const float* er = emb_t + (size_t)d * K_CODES;
        float4 qv;
        qv.x = er[i0]; qv.y = er[i1]; qv.z = er[i2]; qv.w = er[i3];
        *(float4*)(out + ((size_t)(b * 256 + d)) * 1024 + tid * 4) = qv;
    }

    if (oct == 0) {   // 16 blocks accumulate loss (fixed-point u64, deterministic)
        const float4 zn4 = *(const float4*)(znorm + n);
        float lp = 0.f;
#pragma unroll
        for (int j = 0; j < 4; ++j) {
            unsigned int u = (unsigned int)(m[j] >> 32);
            unsigned int fb = (u & 0x80000000u) ? (u ^ 0x80000000u) : ~u;
            lp += __uint_as_float(fb);
        }
        lp += zn4.x + zn4.y + zn4.z + zn4.w;    // ||z||^2 + (||e||^2 - 2 z.e)
#pragma unroll
        for (int off = 32; off >= 1; off >>= 1) lp += __shfl_xor(lp, off);
        __shared__ float red[4];
        const int lane = tid & 63, wv = tid >> 6;
        if (lane == 0) red[wv] = lp;
        __syncthreads();
        if (tid == 0) {
            float bs = red[0] + red[1] + red[2] + red[3];
            u64 fix = (u64)((double)bs * 1048576.0);
            atomicAdd(lsum, fix);
            __threadfence();
            if (atomicAdd(done, 1u) == 15u) {
                u64 tot = atomicAdd(lsum, 0ull);
                loss[0] = (float)((double)tot * (1.25 / (1048576.0 * 4194304.0)));
            }
        }
    }
}

extern "C" void kernel_launch(void* const* d_in, const int* in_sizes, int n_in,
                              void* d_out, int out_size, void* d_ws, size_t ws_size,
                              hipStream_t stream) {
    const float* z   = (const float*)d_in[0];
    const float* emb = (const float*)d_in[1];
    float* out  = (float*)d_out;
    float* loss = out + ZQ_SIZE;

    char* ws = (char*)d_ws;
    ushort_t* Abf = (ushort_t*)(ws);              // 8,388,608 B
    ushort_t* Bbf = (ushort_t*)(ws + 8388608);    //   524,288 B
    float* emb_t  = (float*)(ws + 8912896);       // 1,048,576 B
    float* enorm  = (float*)(ws + 9961472);       //     4,096 B
    float* znorm  = (float*)(ws + 9965568);       //    65,536 B
    u64* part     = (u64*)(ws + 10031104);        //   524,288 B (4 planes x 16384)
    u64* lsum     = (u64*)(ws + 10555392);        //         8 B
    unsigned* done = (unsigned*)(ws + 10555400);  //         4 B

    vq_prep<<<768, 256, 0, stream>>>(z, emb, Abf, znorm, Bbf, enorm, emb_t, lsum, done);
    vq_argmin_mfma<<<256, 512, 0, stream>>>(Abf, Bbf, enorm, part);
    vq_out<<<512, 256, 0, stream>>>(emb_t, part, znorm, out, loss, lsum, done);
}

// Round 6
// 46.235 us; speedup vs baseline: 1.1209x; 1.1209x over previous
//
#include <hip/hip_runtime.h>

// VQ-VAE vector quantizer, MI355X. Granule-planar bf16 layout (no LDS swizzle).
//  Layouts: Ag[g][n] : granule g=d/8 (16B = 8 bf16 d's) of row n; planes of 16384
//           Bg[g][k] : same for codebook, planes of 1024
//  K1 vq_prep : z -> Ag + znorm (coalesced transpose via LDS);
//               emb -> Bg + enorm ; emb -> emb_t[d][k] f32 ; zero lsum/done
//  K2 vq_argmin : 256x256x256 bf16 MFMA tile, dbuf BK=64, XCD-swizzled so all 4
//               n-panels of an m-tile share one XCD L2; planar part[np][row]
//  K3 vq_out : min over 4 planes -> idx; gather via LDS-staged emb_t slice;
//              oct==0 blocks accumulate loss (fixed-point u64), last finalizes
// z: [16,256,32,32] f32, emb_w: [1024,256] f32
// out: z_q f32 (4194304) ++ loss scalar (1 float)

#define K_CODES 1024
#define D_DIM   256
#define N_VEC   16384
#define ZQ_SIZE 4194304

typedef unsigned short ushort_t;
typedef unsigned long long u64;
typedef short bf16x8 __attribute__((ext_vector_type(8)));
typedef float f32x16 __attribute__((ext_vector_type(16)));

__device__ __forceinline__ ushort_t f2bf(float x) {
    unsigned int b = __float_as_uint(x);
    b += 0x7fffu + ((b >> 16) & 1u);   // RNE
    return (ushort_t)(b >> 16);
}

__device__ __forceinline__ void gload_lds16(const void* g, void* l) {
    __builtin_amdgcn_global_load_lds(
        (const __attribute__((address_space(1))) void*)g,
        (__attribute__((address_space(3))) void*)l, 16, 0, 0);
}

// ---------------- K1: prep, blockIdx-branched ----------------
// bid [0,256)   : z -> Ag granule-planar bf16 + znorm[n]   (64 rows per block)
// bid [256,384) : emb -> Bg granule-planar bf16 + enorm    (bid==256: zero lsum/done)
// bid [384,640) : emb -> emb_t[d][k] f32 transpose
__global__ __launch_bounds__(256) void vq_prep(
        const float* __restrict__ z, const float* __restrict__ emb,
        ushort_t* __restrict__ Ag, float* __restrict__ znorm,
        ushort_t* __restrict__ Bg, float* __restrict__ enorm,
        float* __restrict__ emb_t, u64* __restrict__ lsum, unsigned* __restrict__ done) {
    __shared__ float lds[128 * 68 + 256];   // 35.8 KB
    const int bid = blockIdx.x;
    const int tid = threadIdx.x;

    if (bid < 256) {
        // 64 rows n0..n0+63 (one (b, hw-quarter)), 256 d in 2 passes of 128
        const int b = bid >> 4, q = bid & 15;
        const int n0 = b * 1024 + q * 64;
        const float* zb = z + (size_t)b * (256 * 1024) + q * 64;
        const int hw = tid & 63, ds = tid >> 6;
        float zn = 0.f;
#pragma unroll
        for (int p = 0; p < 2; ++p) {
            // load 128 d-rows x 64 hw, coalesced float4; bank-uniform LDS writes
#pragma unroll
            for (int i = 0; i < 8; ++i) {
                const int dl = i * 16 + (tid >> 4);
                const int c  = (tid & 15) * 4;
                const float4 v = *(const float4*)(zb + (size_t)(p * 128 + dl) * 1024 + c);
                *(float4*)(lds + dl * 68 + c) = v;
            }
            __syncthreads();
            // consume: thread (hw, ds) -> 4 granules of 8 consecutive d
#pragma unroll
            for (int i2 = 0; i2 < 4; ++i2) {
                const int dl = ds * 32 + i2 * 8;          // local d base
                const int g  = (p * 128 + dl) >> 3;       // global granule plane
                float v[8];
                ushort_t o[8];
#pragma unroll
                for (int j = 0; j < 8; ++j) {
                    v[j] = lds[(dl + j) * 68 + hw];       // consecutive banks: conflict-free
                    zn += v[j] * v[j];
                    o[j] = f2bf(v[j]);
                }
                *(bf16x8*)(Ag + ((size_t)g * N_VEC + n0 + hw) * 8) = *(bf16x8*)o;  // 1KB/wave
            }
            __syncthreads();
        }
        float* znp = lds + 128 * 68;        // [4][64]
        znp[ds * 64 + hw] = zn;
        __syncthreads();
        if (tid < 64)
            znorm[n0 + tid] = znp[tid] + znp[64 + tid] + znp[128 + tid] + znp[192 + tid];
    } else if (bid < 384) {
        const int gidx = (bid - 256) * 256 + tid;   // [0, 32768)
        const int g = gidx & 31, k = gidx >> 5;
        const float4 v0 = *(const float4*)(emb + k * D_DIM + g * 8);
        const float4 v1 = *(const float4*)(emb + k * D_DIM + g * 8 + 4);
        ushort_t o[8];
        o[0] = f2bf(v0.x); o[1] = f2bf(v0.y); o[2] = f2bf(v0.z); o[3] = f2bf(v0.w);
        o[4] = f2bf(v1.x); o[5] = f2bf(v1.y); o[6] = f2bf(v1.z); o[7] = f2bf(v1.w);
        *(bf16x8*)(Bg + ((size_t)g * K_CODES + k) * 8) = *(bf16x8*)o;
        float s = v0.x * v0.x + v0.y * v0.y + v0.z * v0.z + v0.w * v0.w
                + v1.x * v1.x + v1.y * v1.y + v1.z * v1.z + v1.w * v1.w;
#pragma unroll
        for (int off = 16; off >= 1; off >>= 1) s += __shfl_xor(s, off);
        if ((tid & 31) == 0) enorm[k] = s;
        if (bid == 256 && tid == 0) { *lsum = 0ull; *done = 0u; }
    } else {
        const int t = bid - 384;
        const int kt = t & 31, dt = t >> 5;
        const int c = tid & 31, r4 = tid >> 5;
        const int k0 = kt * 32, d0 = dt * 32;
#pragma unroll
        for (int p = 0; p < 4; ++p) {
            int r = r4 * 4 + p;
            lds[r * 33 + c] = emb[(k0 + r) * D_DIM + d0 + c];
        }
        __syncthreads();
#pragma unroll
        for (int p = 0; p < 4; ++p) {
            int r = r4 * 4 + p;
            emb_t[(d0 + r) * K_CODES + k0 + c] = lds[c * 33 + r];
        }
    }
}

// ---------------- K2: 256x256 MFMA tile -> planar part[np][row] ----------------
__launch_bounds__(512, 2)
__global__ void vq_argmin_mfma(const ushort_t* __restrict__ Ag, const ushort_t* __restrict__ Bg,
                               const float* __restrict__ enorm, u64* __restrict__ part) {
    __shared__ ushort_t As[2][8 * 256 * 8];   // 2 x 32 KB  [cg][row][8]
    __shared__ ushort_t Bs[2][8 * 256 * 8];   // 2 x 32 KB  [cg][code][8]
    __shared__ u64 pmin_lds[256][4];          // 8 KB   (136 KB total)

    const int tid = threadIdx.x;              // 512 threads, 8 waves (2m x 4n)
    const int w = tid >> 6, l = tid & 63;
    const int wm = w >> 2, wn = w & 3;
    const int lane31 = l & 31, hi = l >> 5;
    // XCD swizzle: blocks {x, x+8, x+16, ...} run on XCD x; give XCD x m-tiles
    // [8x, 8x+8) so all 4 n-panels of an m-tile share one L2 (A fetched once).
    const int swz = (blockIdx.x & 7) * 32 + (blockIdx.x >> 3);
    const int mt = swz >> 2, np = swz & 3;
    const int m0 = mt * 256, n0 = np * 256;

    f32x16 acc[4][2];
#pragma unroll
    for (int mi = 0; mi < 4; ++mi)
#pragma unroll
        for (int ni = 0; ni < 2; ++ni)
#pragma unroll
            for (int r = 0; r < 16; ++r) acc[mi][ni][r] = 0.f;

    // stage k-chunk t (64 k = granule planes t*8..t*8+7): linear LDS dest,
    // 1KB-contiguous global reads per wave. No swizzle needed anywhere.
    auto stage = [&](int buf, int t) {
#pragma unroll
        for (int q = 0; q < 4; ++q) {
            int g = q * 512 + tid;            // [0,2048)
            int cg = g >> 8, r = g & 255;
            gload_lds16(Ag + ((size_t)(t * 8 + cg) * N_VEC  + m0 + r) * 8, &As[buf][(size_t)g * 8]);
            gload_lds16(Bg + ((size_t)(t * 8 + cg) * K_CODES + n0 + r) * 8, &Bs[buf][(size_t)g * 8]);
        }
    };

    auto compute = [&](int buf) {
#pragma unroll
        for (int ks = 0; ks < 4; ++ks) {
            const int cgr = ks * 2 + hi;
            bf16x8 a[4], bb[2];
#pragma unroll
            for (int mi = 0; mi < 4; ++mi)
                a[mi] = *(const bf16x8*)(&As[buf][((size_t)cgr * 256 + wm * 128 + mi * 32 + lane31) * 8]);
#pragma unroll
            for (int ni = 0; ni < 2; ++ni)
                bb[ni] = *(const bf16x8*)(&Bs[buf][((size_t)cgr * 256 + wn * 64 + ni * 32 + lane31) * 8]);
#pragma unroll
            for (int mi = 0; mi < 4; ++mi)
#pragma unroll
                for (int ni = 0; ni < 2; ++ni)
                    acc[mi][ni] = __builtin_amdgcn_mfma_f32_32x32x16_bf16(
                        a[mi], bb[ni], acc[mi][ni], 0, 0, 0);
        }
    };

    stage(0, 0);
    __syncthreads();
    for (int t = 0; t < 4; ++t) {
        if (t < 3) stage((t + 1) & 1, t + 1);   // next chunk flies under compute
        compute(t & 1);
        __syncthreads();                         // drains loads + buffer-reuse fence
    }

    // epilogue: score = enorm[k] - 2*dot; pack (score,k); per-wave 32-col min;
    // cross-wave min via LDS; planar coalesced part write (no atomics)
    float en[2]; unsigned int kg[2];
#pragma unroll
    for (int ni = 0; ni < 2; ++ni) {
        int col = n0 + wn * 64 + ni * 32 + lane31;
        en[ni] = enorm[col];
        kg[ni] = (unsigned int)col;
    }
#pragma unroll
    for (int mi = 0; mi < 4; ++mi) {
#pragma unroll
        for (int reg = 0; reg < 16; ++reg) {
            u64 p = ~0ull;
#pragma unroll
            for (int ni = 0; ni < 2; ++ni) {
                float sc = en[ni] - 2.0f * acc[mi][ni][reg];
                unsigned int b = __float_as_uint(sc);
                unsigned int u = b ^ (unsigned int)(((int)b >> 31) | 0x80000000);
                u64 pk = ((u64)u << 32) | kg[ni];
                if (pk < p) p = pk;
            }
#pragma unroll
            for (int off = 16; off >= 1; off >>= 1) {
                u64 q = __shfl_xor(p, off);
                if (q < p) p = q;
            }
            if (lane31 == 0) {
                int rloc = wm * 128 + mi * 32 + (reg & 3) + 8 * (reg >> 2) + 4 * hi;
                pmin_lds[rloc][wn] = p;
            }
        }
    }
    __syncthreads();
    if (tid < 256) {
        u64 a = pmin_lds[tid][0], b = pmin_lds[tid][1];
        u64 c = pmin_lds[tid][2], d = pmin_lds[tid][3];
        u64 m = a < b ? a : b;
        u64 m2 = c < d ? c : d;
        if (m2 < m) m = m2;
        part[(size_t)np * N_VEC + m0 + tid] = m;   // coalesced 2KB store
    }
}

// ---------------- K3: min over planes -> idx -> LDS-staged gather ; loss ----------------
__global__ __launch_bounds__(256) void vq_out(
        const float* __restrict__ emb_t, const u64* __restrict__ part,
        const float* __restrict__ znorm, float* __restrict__ out,
        float* __restrict__ loss, u64* __restrict__ lsum, unsigned* __restrict__ done) {
    __shared__ float et[8 * 1024];              // 32 KB: emb_t rows oct*8..oct*8+7
    const int bid = blockIdx.x, tid = threadIdx.x;
    const int b = bid >> 5, oct = bid & 31;     // 16 b x 32 d-octets
    const int n = b * 1024 + tid * 4;           // this thread's 4 rows == its 4 hw cols

    // stage emb_t slice (coalesced, L2-hot: 16 blocks share each slice)
#pragma unroll
    for (int p = 0; p < 8; ++p) {
        int g = p * 256 + tid;                  // [0,2048) 16B granules
        gload_lds16(emb_t + (size_t)oct * 8192 + g * 4, &et[g * 4]);
    }

    u64 m[4];
    {
        ulonglong2 p0 = *(const ulonglong2*)(part + 0 * N_VEC + n);
        ulonglong2 p1 = *(const ulonglong2*)(part + 0 * N_VEC + n + 2);
        m[0] = p0.x; m[1] = p0.y; m[2] = p1.x; m[3] = p1.y;
    }
#pragma unroll
    for (int np = 1; np < 4; ++np) {
        ulonglong2 p0 = *(const ulonglong2*)(part + (size_t)np * N_VEC + n);
        ulonglong2 p1 = *(const ulonglong2*)(part + (size_t)np * N_VEC + n + 2);
        if (p0.x < m[0]) m[0] = p0.x;
        if (p0.y < m[1]) m[1] = p0.y;
        if (p1.x < m[2]) m[2] = p1.x;
        if (p1.y < m[3]) m[3] = p1.y;
    }
    const unsigned i0 = (unsigned)(m[0] & 0xffffffffu), i1 = (unsigned)(m[1] & 0xffffffffu);
    const unsigned i2 = (unsigned)(m[2] & 0xffffffffu), i3 = (unsigned)(m[3] & 0xffffffffu);

    __syncthreads();   // staging complete

    // gather from LDS (random k -> ~2-way bank aliasing, free) + coalesced stores
#pragma unroll
    for (int d8 = 0; d8 < 8; ++d8) {
        const float* er = et + d8 * 1024;
        float4 qv;
        qv.x = er[i0]; qv.y = er[i1]; qv.z = er[i2]; qv.w = er[i3];
        *(float4*)(out + ((size_t)(b * 256 + oct * 8 + d8)) * 1024 + tid * 4) = qv;
    }

    if (oct == 0) {   // 16 blocks accumulate loss (fixed-point u64, deterministic)
        const float4 zn4 = *(const float4*)(znorm + n);
        float lp = 0.f;
#pragma unroll
        for (int j = 0; j < 4; ++j) {
            unsigned int u = (unsigned int)(m[j] >> 32);
            unsigned int fb = (u & 0x80000000u) ? (u ^ 0x80000000u) : ~u;
            lp += __uint_as_float(fb);
        }
        lp += zn4.x + zn4.y + zn4.z + zn4.w;    // ||z||^2 + (||e||^2 - 2 z.e)
#pragma unroll
        for (int off = 32; off >= 1; off >>= 1) lp += __shfl_xor(lp, off);
        __shared__ float red[4];
        const int lane = tid & 63, wv = tid >> 6;
        if (lane == 0) red[wv] = lp;
        __syncthreads();
        if (tid == 0) {
            float bs = red[0] + red[1] + red[2] + red[3];
            u64 fix = (u64)((double)bs * 1048576.0);
            atomicAdd(lsum, fix);
            __threadfence();
            if (atomicAdd(done, 1u) == 15u) {
                u64 tot = atomicAdd(lsum, 0ull);
                loss[0] = (float)((double)tot * (1.25 / (1048576.0 * 4194304.0)));
            }
        }
    }
}

extern "C" void kernel_launch(void* const* d_in, const int* in_sizes, int n_in,
                              void* d_out, int out_size, void* d_ws, size_t ws_size,
                              hipStream_t stream) {
    const float* z   = (const float*)d_in[0];
    const float* emb = (const float*)d_in[1];
    float* out  = (float*)d_out;
    float* loss = out + ZQ_SIZE;

    char* ws = (char*)d_ws;
    ushort_t* Ag  = (ushort_t*)(ws);              // 8,388,608 B  [32][16384] granules
    ushort_t* Bg  = (ushort_t*)(ws + 8388608);    //   524,288 B  [32][1024] granules
    float* emb_t  = (float*)(ws + 8912896);       // 1,048,576 B
    float* enorm  = (float*)(ws + 9961472);       //     4,096 B
    float* znorm  = (float*)(ws + 9965568);       //    65,536 B
    u64* part     = (u64*)(ws + 10031104);        //   524,288 B (4 planes x 16384)
    u64* lsum     = (u64*)(ws + 10555392);        //         8 B
    unsigned* done = (unsigned*)(ws + 10555400);  //         4 B

    vq_prep<<<640, 256, 0, stream>>>(z, emb, Ag, znorm, Bg, enorm, emb_t, lsum, done);
    vq_argmin_mfma<<<256, 512, 0, stream>>>(Ag, Bg, enorm, part);
    vq_out<<<512, 256, 0, stream>>>(emb_t, part, znorm, out, loss, lsum, done);
}